// Round 1
// baseline (402.024 us; speedup 1.0000x reference)
//
#include <hip/hip_runtime.h>
#include <hip/hip_bf16.h>

#define B_ 32
#define T_ 2048
#define N_ 128
#define K_ 5
#define BN_ (B_ * N_)
#define PMAX_ 512
#define MINP_ 2

static constexpr double PI_D = 3.14159265358979323846264338327950288;

// ---------------------------------------------------------------------------
// Kernel A: transpose x[B,T,N] -> seq rows stored at out[(bn*K+0)*T .. +T)
// ---------------------------------------------------------------------------
__global__ __launch_bounds__(256) void pt_transpose(const float* __restrict__ x,
                                                    float* __restrict__ out) {
    __shared__ float tile[32][33];
    const int b  = blockIdx.z;
    const int t0 = blockIdx.x * 32;
    const int n0 = blockIdx.y * 32;
    const int tx = threadIdx.x;   // 0..31
    const int ty = threadIdx.y;   // 0..7

#pragma unroll
    for (int j = 0; j < 4; ++j) {
        const int t = t0 + ty + 8 * j;
        tile[ty + 8 * j][tx] = x[((size_t)b * T_ + t) * N_ + (n0 + tx)];
    }
    __syncthreads();
#pragma unroll
    for (int j = 0; j < 4; ++j) {
        const int n = n0 + ty + 8 * j;
        const size_t bn = (size_t)b * N_ + n;
        out[bn * (K_ * (size_t)T_) + (t0 + tx)] = tile[tx][ty + 8 * j];
    }
}

// ---------------------------------------------------------------------------
// Kernel B: per-sequence fp64 FFT -> top-5 -> periods/cycles -> tile rows
// ---------------------------------------------------------------------------
__global__ __launch_bounds__(256) void pt_fft_tiles(float* __restrict__ out) {
    __shared__ double re[2048];
    __shared__ double im[2048];
    __shared__ double twr[1024];
    __shared__ double twi[1024];
    __shared__ float  seq[2048];
    __shared__ double rval[256];
    __shared__ int    ridx[256];
    __shared__ int    sh_per[K_], sh_cyc[K_], sh_take[K_];

    const int bn  = blockIdx.x;
    const int tid = threadIdx.x;
    float* row0 = out + (size_t)bn * (K_ * T_);

    // Load this sequence (written by pt_transpose) into LDS.
    for (int i = tid; i < T_; i += 256) seq[i] = row0[i];

    // Twiddle table: tw[m] = exp(-2*pi*i*m/2048), m = 0..1023 (double).
    for (int m = tid; m < 1024; m += 256) {
        double s, c;
        sincos(-2.0 * PI_D * (double)m / 2048.0, &s, &c);
        twr[m] = c;
        twi[m] = s;
    }
    __syncthreads();

    // Bit-reversed copy into (re, im), im = 0.
    for (int i = tid; i < T_; i += 256) {
        const int r = (int)(__brev((unsigned)i) >> 21);   // 11-bit reverse
        re[i] = (double)seq[r];
        im[i] = 0.0;
    }
    __syncthreads();

    // In-place radix-2 DIT, 11 stages.
    for (int s = 1; s <= 11; ++s) {
        const int half   = 1 << (s - 1);
        const int tshift = 11 - s;
        for (int t = tid; t < 1024; t += 256) {
            const int j   = t & (half - 1);
            const int g   = t >> (s - 1);
            const int pos = (g << s) + j;
            const double wr = twr[j << tshift];
            const double wi = twi[j << tshift];
            const double ur = re[pos],        ui = im[pos];
            const double vr = re[pos + half], vi = im[pos + half];
            const double tr = vr * wr - vi * wi;
            const double ti = vr * wi + vi * wr;
            re[pos]        = ur + tr;
            im[pos]        = ui + ti;
            re[pos + half] = ur - tr;
            im[pos + half] = ui - ti;
        }
        __syncthreads();
    }

    // mag^2 into re[k] for k=1..1024; DC excluded via sentinel.
    for (int k = tid; k <= 1024; k += 256) {
        const double m2 = re[k] * re[k] + im[k] * im[k];
        re[k] = (k == 0) ? -1.0 : m2;
    }
    __syncthreads();

    // Top-5 (descending value, smaller index wins ties — matches lax.top_k).
    for (int it = 0; it < K_; ++it) {
        double bestv = -2.0;
        int    besti = 1 << 30;
        for (int k = 1 + tid; k <= 1024; k += 256) {
            const double v = re[k];
            if (v > bestv || (v == bestv && k < besti)) { bestv = v; besti = k; }
        }
        rval[tid] = bestv;
        ridx[tid] = besti;
        __syncthreads();
        for (int off = 128; off > 0; off >>= 1) {
            if (tid < off) {
                const double v2 = rval[tid + off];
                const int    i2 = ridx[tid + off];
                if (v2 > rval[tid] || (v2 == rval[tid] && i2 < ridx[tid])) {
                    rval[tid] = v2;
                    ridx[tid] = i2;
                }
            }
            __syncthreads();
        }
        if (tid == 0) {
            const int kb = ridx[0];
            re[kb] = -1.0;                       // exclude for next iteration
            int kidx = kb < 1 ? 1 : kb;
            int period = T_ / kidx;
            if (period > PMAX_) period = PMAX_;
            if (period < MINP_) period = MINP_;
            if (period < 1) period = 1;
            int cyc = T_ / period;
            if (cyc < 1) cyc = 1;
            sh_per[it]  = period;
            sh_cyc[it]  = cyc;
            sh_take[it] = period * cyc;
        }
        __syncthreads();
    }

    // periods / cycles (int values written as float32).
    const size_t TILES = (size_t)BN_ * K_ * T_;
    if (tid < K_) {
        out[TILES + (size_t)bn * K_ + tid]                      = (float)sh_per[tid];
        out[TILES + (size_t)BN_ * K_ + (size_t)bn * K_ + tid]   = (float)sh_cyc[tid];
    }

    // Tile rows: tiles[bn,k,t] = (t < take) ? seq[start + t] : 0, float4 stores.
    for (int e = tid; e < K_ * (T_ / 4); e += 256) {
        const int k    = e >> 9;            // / 512
        const int p4   = (e & 511) << 2;    // element offset within row
        const int take  = sh_take[k];
        const int start = T_ - take;
        float4 v;
        v.x = (p4 + 0 < take) ? seq[start + p4 + 0] : 0.0f;
        v.y = (p4 + 1 < take) ? seq[start + p4 + 1] : 0.0f;
        v.z = (p4 + 2 < take) ? seq[start + p4 + 2] : 0.0f;
        v.w = (p4 + 3 < take) ? seq[start + p4 + 3] : 0.0f;
        *(float4*)(row0 + (size_t)k * T_ + p4) = v;
    }
}

// ---------------------------------------------------------------------------
extern "C" void kernel_launch(void* const* d_in, const int* in_sizes, int n_in,
                              void* d_out, int out_size, void* d_ws, size_t ws_size,
                              hipStream_t stream) {
    const float* x = (const float*)d_in[0];
    float* out = (float*)d_out;

    dim3 gridA(T_ / 32, N_ / 32, B_);
    dim3 blockA(32, 8, 1);
    pt_transpose<<<gridA, blockA, 0, stream>>>(x, out);

    pt_fft_tiles<<<dim3(BN_), dim3(256), 0, stream>>>(out);
}

// Round 2
// 267.826 us; speedup vs baseline: 1.5011x; 1.5011x over previous
//
#include <hip/hip_runtime.h>
#include <hip/hip_bf16.h>

#define B_ 32
#define T_ 2048
#define N_ 128
#define K_ 5
#define BN_ (B_ * N_)
#define PMAX_ 512
#define MINP_ 2

static constexpr double PI_D = 3.14159265358979323846264338327950288;

// ---------------------------------------------------------------------------
// Kernel 0: twiddle table tw[m] = exp(-2*pi*i*m/2048), m=0..1023, into d_ws.
// ---------------------------------------------------------------------------
__global__ __launch_bounds__(256) void pt_twiddle(double* __restrict__ tw) {
    const int m = blockIdx.x * 256 + threadIdx.x;
    if (m < 1024) {
        double s, c;
        sincos(-2.0 * PI_D * (double)m / 2048.0, &s, &c);
        tw[2 * m + 0] = c;
        tw[2 * m + 1] = s;
    }
}

// ---------------------------------------------------------------------------
// Kernel A: transpose x[B,T,N] -> seq rows at out[(bn*K+0)*T .. +T)
// 64x64 tiles, float4 global on both sides, stride-65 LDS (conflict-free).
// ---------------------------------------------------------------------------
__global__ __launch_bounds__(256) void pt_transpose(const float* __restrict__ x,
                                                    float* __restrict__ out) {
    __shared__ float tile[64 * 65];
    const int b  = blockIdx.z;
    const int t0 = blockIdx.x * 64;
    const int n0 = blockIdx.y * 64;
    const int c  = threadIdx.x & 15;    // 0..15
    const int rq = threadIdx.x >> 4;    // 0..15

#pragma unroll
    for (int j = 0; j < 4; ++j) {
        const int tl = rq + 16 * j;
        const float4 v = *(const float4*)&x[((size_t)(b * T_ + t0 + tl)) * N_ + n0 + 4 * c];
        float* p = &tile[tl * 65 + 4 * c];
        p[0] = v.x; p[1] = v.y; p[2] = v.z; p[3] = v.w;
    }
    __syncthreads();
#pragma unroll
    for (int j = 0; j < 4; ++j) {
        const int nl = rq + 16 * j;
        const int tb = 4 * c;
        float4 v;
        v.x = tile[(tb + 0) * 65 + nl];
        v.y = tile[(tb + 1) * 65 + nl];
        v.z = tile[(tb + 2) * 65 + nl];
        v.w = tile[(tb + 3) * 65 + nl];
        const size_t bn = (size_t)b * N_ + n0 + nl;
        *(float4*)&out[bn * (size_t)(K_ * T_) + t0 + tb] = v;
    }
}

// ---------------------------------------------------------------------------
// Kernel B: per-PAIR-of-sequences fp64 FFT (z = a + i*b) -> unpack mag^2 for
// both -> top-5 each (two 128-thread halves) -> periods/cycles -> tile rows.
// ---------------------------------------------------------------------------
__global__ __launch_bounds__(256) void pt_fft_tiles(float* __restrict__ out,
                                                    const double* __restrict__ tw) {
    __shared__ double re[2048];
    __shared__ double im[2048];
    __shared__ float  seqA[2048];
    __shared__ float  seqB[2048];
    __shared__ double rval[256];
    __shared__ int    ridx[256];
    __shared__ int    sh_per[2][K_], sh_cyc[2][K_], sh_take[2][K_];

    const int bn0 = blockIdx.x * 2;
    const int tid = threadIdx.x;
    float* rowA = out + (size_t)bn0 * (K_ * T_);
    float* rowB = rowA + (size_t)(K_ * T_);

    // Load both sequences (written by pt_transpose), vectorized.
    for (int i = tid; i < T_ / 4; i += 256) {
        ((float4*)seqA)[i] = ((const float4*)rowA)[i];
        ((float4*)seqB)[i] = ((const float4*)rowB)[i];
    }
    __syncthreads();

    // Bit-reversed pack: z[i] = a[rev(i)] + i*b[rev(i)].
    for (int i = tid; i < T_; i += 256) {
        const int r = (int)(__brev((unsigned)i) >> 21);   // 11-bit reverse
        re[i] = (double)seqA[r];
        im[i] = (double)seqB[r];
    }
    __syncthreads();

    // In-place radix-2 DIT, 11 stages, twiddles from global (L1-resident).
    for (int s = 1; s <= 11; ++s) {
        const int half   = 1 << (s - 1);
        const int tshift = 11 - s;
        for (int t = tid; t < 1024; t += 256) {
            const int j   = t & (half - 1);
            const int g   = t >> (s - 1);
            const int pos = (g << s) + j;
            const int tm  = j << tshift;
            const double wr = tw[2 * tm + 0];
            const double wi = tw[2 * tm + 1];
            const double ur = re[pos],        ui = im[pos];
            const double vr = re[pos + half], vi = im[pos + half];
            const double tr = vr * wr - vi * wi;
            const double ti = vr * wi + vi * wr;
            re[pos]        = ur + tr;
            im[pos]        = ui + ti;
            re[pos + half] = ur - tr;
            im[pos + half] = ui - ti;
        }
        __syncthreads();
    }

    // Unpack both spectra; store 4*mag^2 (uniform scale, rank-preserving):
    // A[k] ~ (Zr[k]+Zr[N-k], Zi[k]-Zi[N-k]);  B[k] ~ (Zi[k]+Zi[N-k], Zr[N-k]-Zr[k])
    double magsA[4], magsB[4];
#pragma unroll
    for (int i = 0; i < 4; ++i) {
        const int k  = 1 + tid + 256 * i;   // 1..1024
        const int nk = 2048 - k;
        const double zr = re[k],  zi = im[k];
        const double yr = re[nk], yi = im[nk];
        const double ar = zr + yr, ai = zi - yi;
        const double br = zi + yi, bi = yr - zr;
        magsA[i] = ar * ar + ai * ai;
        magsB[i] = br * br + bi * bi;
    }
    __syncthreads();
#pragma unroll
    for (int i = 0; i < 4; ++i) {
        const int k = 1 + tid + 256 * i;
        re[k] = magsA[i];
        im[k] = magsB[i];
    }
    __syncthreads();

    // Top-5, two halves: threads 0..127 -> seq A (re), 128..255 -> seq B (im).
    const int h  = tid >> 7;
    const int lt = tid & 127;
    double* marr = h ? im : re;
    for (int it = 0; it < K_; ++it) {
        double bestv = -2.0;
        int    besti = 1 << 30;
        for (int k = 1 + lt; k <= 1024; k += 128) {
            const double v = marr[k];
            if (v > bestv || (v == bestv && k < besti)) { bestv = v; besti = k; }
        }
        rval[tid] = bestv;
        ridx[tid] = besti;
        __syncthreads();
        for (int off = 64; off > 0; off >>= 1) {
            if (lt < off) {
                const double v2 = rval[tid + off];
                const int    i2 = ridx[tid + off];
                if (v2 > rval[tid] || (v2 == rval[tid] && i2 < ridx[tid])) {
                    rval[tid] = v2;
                    ridx[tid] = i2;
                }
            }
            __syncthreads();
        }
        if (lt == 0) {
            const int kb = ridx[tid];        // >= 1
            marr[kb] = -1.0;                 // exclude for next iteration
            int period = T_ / kb;
            if (period > PMAX_) period = PMAX_;
            if (period < MINP_) period = MINP_;
            int cyc = T_ / period;
            if (cyc < 1) cyc = 1;
            sh_per[h][it]  = period;
            sh_cyc[h][it]  = cyc;
            sh_take[h][it] = period * cyc;
        }
        __syncthreads();
    }

    // periods / cycles (int values written as float32).
    const size_t TILES = (size_t)BN_ * K_ * T_;
    if (tid < 2 * K_) {
        const int s  = tid / K_;
        const int k2 = tid % K_;
        out[TILES + (size_t)(bn0 + s) * K_ + k2]                    = (float)sh_per[s][k2];
        out[TILES + (size_t)BN_ * K_ + (size_t)(bn0 + s) * K_ + k2] = (float)sh_cyc[s][k2];
    }

    // Tile rows for both sequences, float4 stores.
    for (int e = tid; e < 2 * K_ * (T_ / 4); e += 256) {
        const int s    = (e >= K_ * (T_ / 4)) ? 1 : 0;
        const int w    = e - s * (K_ * (T_ / 4));
        const int k    = w >> 9;            // / 512
        const int p4   = (w & 511) << 2;    // element offset within row
        const int take  = sh_take[s][k];
        const int start = T_ - take;
        const float* sq = s ? seqB : seqA;
        float4 v;
        v.x = (p4 + 0 < take) ? sq[start + p4 + 0] : 0.0f;
        v.y = (p4 + 1 < take) ? sq[start + p4 + 1] : 0.0f;
        v.z = (p4 + 2 < take) ? sq[start + p4 + 2] : 0.0f;
        v.w = (p4 + 3 < take) ? sq[start + p4 + 3] : 0.0f;
        float* dst = (s ? rowB : rowA) + (size_t)k * T_ + p4;
        *(float4*)dst = v;
    }
}

// ---------------------------------------------------------------------------
extern "C" void kernel_launch(void* const* d_in, const int* in_sizes, int n_in,
                              void* d_out, int out_size, void* d_ws, size_t ws_size,
                              hipStream_t stream) {
    const float* x = (const float*)d_in[0];
    float* out = (float*)d_out;
    double* tw = (double*)d_ws;   // 16 KB twiddle table

    pt_twiddle<<<dim3(4), dim3(256), 0, stream>>>(tw);

    dim3 gridA(T_ / 64, N_ / 64, B_);
    pt_transpose<<<gridA, dim3(256), 0, stream>>>(x, out);

    pt_fft_tiles<<<dim3(BN_ / 2), dim3(256), 0, stream>>>(out, tw);
}

// Round 4
// 245.235 us; speedup vs baseline: 1.6393x; 1.0921x over previous
//
#include <hip/hip_runtime.h>

#define B_ 32
#define T_ 2048
#define N_ 128
#define K_ 5
#define BN_ (B_ * N_)
#define PMAX_ 512
#define MINP_ 2

static constexpr double PI_D = 3.14159265358979323846264338327950288;
static constexpr double S2_D = 0.70710678118654752440084436210485;  // sqrt(1/2)

typedef float nfloat4 __attribute__((ext_vector_type(4)));  // native vec for NT store

struct cd { double r, i; };

__device__ __forceinline__ void bf_w(cd& u, cd& v, double wr, double wi) {
    const double tr = v.r * wr - v.i * wi;
    const double ti = v.r * wi + v.i * wr;
    v.r = u.r - tr; v.i = u.i - ti;
    u.r += tr;      u.i += ti;
}
__device__ __forceinline__ void bf_1(cd& u, cd& v) {        // w = 1
    const double tr = v.r, ti = v.i;
    v.r = u.r - tr; v.i = u.i - ti;
    u.r += tr;      u.i += ti;
}
__device__ __forceinline__ void bf_mi(cd& u, cd& v) {       // w = -i
    const double tr = v.i, ti = -v.r;
    v.r = u.r - tr; v.i = u.i - ti;
    u.r += tr;      u.i += ti;
}
// LDS bank swizzle for the fp64 re/im arrays: every hot access pattern <=4-way.
__device__ __forceinline__ int sw(int i) { return i ^ ((i >> 5) & 31); }

// ---------------------------------------------------------------------------
// Kernel 0: twiddle table tw[m] = exp(-2*pi*i*m/2048), m=0..1023, into d_ws.
// ---------------------------------------------------------------------------
__global__ __launch_bounds__(256) void pt_twiddle(double2* __restrict__ tw) {
    const int m = blockIdx.x * 256 + threadIdx.x;
    if (m < 1024) {
        double s, c;
        sincos(-2.0 * PI_D * (double)m / 2048.0, &s, &c);
        tw[m] = make_double2(c, s);
    }
}

// ---------------------------------------------------------------------------
// Main kernel: per-PAIR-of-sequences. Reads x columns directly (transpose
// fused), fp64 radix-8 FFT (z = a + i*b), unpack mag^2, top-5 per series,
// periods/cycles, tile rows.
// ---------------------------------------------------------------------------
__global__ __launch_bounds__(256, 3) void pt_fft_tiles(const float* __restrict__ x,
                                                       float* __restrict__ out,
                                                       const double2* __restrict__ tw) {
    __shared__ double re[2048];
    __shared__ double im[2048];
    __shared__ __align__(16) float seqA[2052];   // +4 slack for shifted f4 reads
    __shared__ __align__(16) float seqB[2052];
    __shared__ double wredv[4];
    __shared__ int    wredi[4];
    __shared__ int sh_per[2][K_], sh_cyc[2][K_], sh_take[2][K_];

    // XCD-aware swizzle: blocks with equal (blockIdx & 7) (likely same XCD)
    // get consecutive q -> adjacent x columns -> L2 line reuse.
    const int i0  = blockIdx.x;
    const int q   = ((i0 & 7) << 8) | (i0 >> 3);
    const int bn0 = q * 2;
    const int b   = bn0 >> 7;          // / N_
    const int n   = bn0 & 127;         // even
    const int tid = threadIdx.x;

    // ---- Load x columns (n, n+1): seq arrays + bit-reversed complex pack.
    const float* xp = x + (size_t)b * T_ * N_ + n;
#pragma unroll
    for (int m = 0; m < 8; ++m) {
        const int t = tid + 256 * m;
        const float2 v = *(const float2*)(xp + (size_t)t * N_);
        seqA[t] = v.x;
        seqB[t] = v.y;
        const int p = sw((int)(__brev((unsigned)t) >> 21));   // pos = rev11(t)
        re[p] = (double)v.x;
        im[p] = (double)v.y;
    }
    __syncthreads();

    // ---- Round 1: radix-8 (stages 1-3), h=1, constant twiddles.
    {
        const int base = tid * 8;
        cd E[8];
#pragma unroll
        for (int j = 0; j < 8; ++j) { const int p = sw(base + j); E[j].r = re[p]; E[j].i = im[p]; }
        bf_1(E[0], E[1]); bf_1(E[2], E[3]); bf_1(E[4], E[5]); bf_1(E[6], E[7]);
        bf_1(E[0], E[2]); bf_mi(E[1], E[3]); bf_1(E[4], E[6]); bf_mi(E[5], E[7]);
        bf_1(E[0], E[4]); bf_w(E[1], E[5], S2_D, -S2_D);
        bf_mi(E[2], E[6]); bf_w(E[3], E[7], -S2_D, -S2_D);
#pragma unroll
        for (int j = 0; j < 8; ++j) { const int p = sw(base + j); re[p] = E[j].r; im[p] = E[j].i; }
    }
    __syncthreads();

    // ---- Rounds 2,3: radix-8 at stages s=4 (h=8) and s=7 (h=64).
#pragma unroll
    for (int r = 0; r < 2; ++r) {
        const int s    = 4 + 3 * r;
        const int h    = 1 << (s - 1);
        const int bq   = tid & (h - 1);
        const int g    = tid >> (s - 1);
        const int base = g * 8 * h + bq;
        const double2 w1  = tw[bq << (11 - s)];
        const double2 w2a = tw[bq << (10 - s)];
        const double2 w2b = tw[(bq + h) << (10 - s)];
        const double2 w30 = tw[bq << (9 - s)];
        const double2 w31 = tw[(bq + h) << (9 - s)];
        const double2 w32 = tw[(bq + 2 * h) << (9 - s)];
        const double2 w33 = tw[(bq + 3 * h) << (9 - s)];
        cd E[8];
#pragma unroll
        for (int j = 0; j < 8; ++j) { const int p = sw(base + j * h); E[j].r = re[p]; E[j].i = im[p]; }
        bf_w(E[0], E[1], w1.x, w1.y);   bf_w(E[2], E[3], w1.x, w1.y);
        bf_w(E[4], E[5], w1.x, w1.y);   bf_w(E[6], E[7], w1.x, w1.y);
        bf_w(E[0], E[2], w2a.x, w2a.y); bf_w(E[1], E[3], w2b.x, w2b.y);
        bf_w(E[4], E[6], w2a.x, w2a.y); bf_w(E[5], E[7], w2b.x, w2b.y);
        bf_w(E[0], E[4], w30.x, w30.y); bf_w(E[1], E[5], w31.x, w31.y);
        bf_w(E[2], E[6], w32.x, w32.y); bf_w(E[3], E[7], w33.x, w33.y);
#pragma unroll
        for (int j = 0; j < 8; ++j) { const int p = sw(base + j * h); re[p] = E[j].r; im[p] = E[j].i; }
        __syncthreads();
    }

    // ---- Round 4: radix-4 (stages 10-11), h=512, 2 butterflies/thread.
#pragma unroll
    for (int u = 0; u < 2; ++u) {
        const int bb = tid + 256 * u;
        const double2 wA = tw[bb << 1];
        const double2 wB = tw[bb];
        const double2 wC = tw[bb + 512];
        const int p0 = sw(bb), p1 = sw(bb + 512), p2 = sw(bb + 1024), p3 = sw(bb + 1536);
        cd E0 = {re[p0], im[p0]}, E1 = {re[p1], im[p1]};
        cd E2 = {re[p2], im[p2]}, E3 = {re[p3], im[p3]};
        bf_w(E0, E1, wA.x, wA.y); bf_w(E2, E3, wA.x, wA.y);
        bf_w(E0, E2, wB.x, wB.y); bf_w(E1, E3, wC.x, wC.y);
        re[p0] = E0.r; im[p0] = E0.i; re[p1] = E1.r; im[p1] = E1.i;
        re[p2] = E2.r; im[p2] = E2.i; re[p3] = E3.r; im[p3] = E3.i;
    }
    __syncthreads();

    // ---- Unpack both spectra; 4*mag^2 (uniform scale, rank-preserving).
    double magsA[4], magsB[4];
#pragma unroll
    for (int m = 0; m < 4; ++m) {
        const int k  = 1 + tid + 256 * m;          // 1..1024
        const int nk = 2048 - k;
        const int pk = sw(k), pn = sw(nk);
        const double zr = re[pk], zi = im[pk];
        const double yr = re[pn], yi = im[pn];
        const double ar = zr + yr, ai = zi - yi;
        const double br = zi + yi, bi = yr - zr;
        magsA[m] = ar * ar + ai * ai;
        magsB[m] = br * br + bi * bi;
    }
    __syncthreads();
#pragma unroll
    for (int m = 0; m < 4; ++m) {
        const int pk = sw(1 + tid + 256 * m);
        re[pk] = magsA[m];
        im[pk] = magsB[m];
    }
    __syncthreads();

    // ---- Top-5: threads 0..127 -> A (re), 128..255 -> B (im); shuffle reduce.
    const int half = tid >> 7;
    const int lt   = tid & 127;
    const int wid  = tid >> 6;
    double* marr = half ? im : re;
    for (int it = 0; it < K_; ++it) {
        double bestv = -2.0;
        int    besti = 1 << 30;
#pragma unroll
        for (int m = 0; m < 8; ++m) {
            const int k = 1 + lt + 128 * m;        // 1..1024
            const double v = marr[sw(k)];
            if (v > bestv || (v == bestv && k < besti)) { bestv = v; besti = k; }
        }
#pragma unroll
        for (int off = 32; off > 0; off >>= 1) {
            const double v2 = __shfl_down(bestv, off);
            const int    i2 = __shfl_down(besti, off);
            if (v2 > bestv || (v2 == bestv && i2 < besti)) { bestv = v2; besti = i2; }
        }
        if ((tid & 63) == 0) { wredv[wid] = bestv; wredi[wid] = besti; }
        __syncthreads();
        if (lt == 0) {
            double vb = wredv[2 * half]; int ib = wredi[2 * half];
            const double v1 = wredv[2 * half + 1]; const int i1 = wredi[2 * half + 1];
            if (v1 > vb || (v1 == vb && i1 < ib)) { vb = v1; ib = i1; }
            marr[sw(ib)] = -1.0;                   // exclude for next iter
            int period = T_ / ib;
            if (period > PMAX_) period = PMAX_;
            if (period < MINP_) period = MINP_;
            const int cyc = T_ / period;
            sh_per[half][it]  = period;
            sh_cyc[half][it]  = cyc;
            sh_take[half][it] = period * cyc;
        }
        __syncthreads();
    }

    // ---- periods / cycles (ints as float32).
    const size_t TILES = (size_t)BN_ * K_ * T_;
    if (tid < 2 * K_) {
        const int s2 = tid / K_, k2 = tid % K_;
        out[TILES + (size_t)(bn0 + s2) * K_ + k2]                      = (float)sh_per[s2][k2];
        out[TILES + (size_t)BN_ * K_ + (size_t)(bn0 + s2) * K_ + k2]   = (float)sh_cyc[s2][k2];
    }

    // ---- Tile rows: aligned f4 LDS reads + register shift, f4 NT stores.
    float* rowA = out + (size_t)bn0 * (K_ * T_);
#pragma unroll
    for (int m = 0; m < 20; ++m) {
        const int e  = tid + 256 * m;
        const int s2 = (e >= K_ * (T_ / 4)) ? 1 : 0;
        const int w  = e - s2 * (K_ * (T_ / 4));
        const int k  = w >> 9;                     // / 512
        const int p4 = (w & 511) << 2;
        const int take  = sh_take[s2][k];
        const int start = T_ - take;
        const float4* sq4 = (const float4*)(s2 ? seqB : seqA);
        const int idx = start + p4;
        int a0 = idx >> 2;
        if (a0 > 511) a0 = 511;                    // clamp (masked anyway)
        const int sh = idx & 3;
        const float4 lo = sq4[a0];
        const float4 hi = sq4[a0 + 1];
        float r0, r1, r2, r3;
        if (sh == 0)      { r0 = lo.x; r1 = lo.y; r2 = lo.z; r3 = lo.w; }
        else if (sh == 1) { r0 = lo.y; r1 = lo.z; r2 = lo.w; r3 = hi.x; }
        else if (sh == 2) { r0 = lo.z; r1 = lo.w; r2 = hi.x; r3 = hi.y; }
        else              { r0 = lo.w; r1 = hi.x; r2 = hi.y; r3 = hi.z; }
        nfloat4 v;
        v.x = (p4 + 0 < take) ? r0 : 0.0f;
        v.y = (p4 + 1 < take) ? r1 : 0.0f;
        v.z = (p4 + 2 < take) ? r2 : 0.0f;
        v.w = (p4 + 3 < take) ? r3 : 0.0f;
        __builtin_nontemporal_store(v, (nfloat4*)(rowA + (size_t)(s2 * K_ + k) * T_ + p4));
    }
}

// ---------------------------------------------------------------------------
extern "C" void kernel_launch(void* const* d_in, const int* in_sizes, int n_in,
                              void* d_out, int out_size, void* d_ws, size_t ws_size,
                              hipStream_t stream) {
    const float* x = (const float*)d_in[0];
    float* out = (float*)d_out;
    double2* tw = (double2*)d_ws;   // 16 KB twiddle table

    pt_twiddle<<<dim3(4), dim3(256), 0, stream>>>(tw);
    pt_fft_tiles<<<dim3(BN_ / 2), dim3(256), 0, stream>>>(x, out, tw);
}

// Round 5
// 232.391 us; speedup vs baseline: 1.7299x; 1.0553x over previous
//
#include <hip/hip_runtime.h>

#define B_ 32
#define T_ 2048
#define N_ 128
#define K_ 5
#define BN_ (B_ * N_)
#define PMAX_ 512
#define MINP_ 2

static constexpr double PI_D = 3.14159265358979323846264338327950288;
static constexpr double S2_D = 0.70710678118654752440084436210485;  // sqrt(1/2)

struct cd { double r, i; };

__device__ __forceinline__ void bf_w(cd& u, cd& v, double wr, double wi) {
    const double tr = v.r * wr - v.i * wi;
    const double ti = v.r * wi + v.i * wr;
    v.r = u.r - tr; v.i = u.i - ti;
    u.r += tr;      u.i += ti;
}
__device__ __forceinline__ void bf_1(cd& u, cd& v) {        // w = 1
    const double tr = v.r, ti = v.i;
    v.r = u.r - tr; v.i = u.i - ti;
    u.r += tr;      u.i += ti;
}
__device__ __forceinline__ void bf_mi(cd& u, cd& v) {       // w = -i
    const double tr = v.i, ti = -v.r;
    v.r = u.r - tr; v.i = u.i - ti;
    u.r += tr;      u.i += ti;
}
// LDS bank swizzle for the fp64 re/im arrays: every hot access pattern <=4-way.
__device__ __forceinline__ int sw(int i) { return i ^ ((i >> 5) & 31); }

// ---------------------------------------------------------------------------
// Kernel 0: twiddle table tw[m] = exp(-2*pi*i*m/2048), m=0..1023, into d_ws.
// ---------------------------------------------------------------------------
__global__ __launch_bounds__(256) void pt_twiddle(double2* __restrict__ tw) {
    const int m = blockIdx.x * 256 + threadIdx.x;
    if (m < 1024) {
        double s, c;
        sincos(-2.0 * PI_D * (double)m / 2048.0, &s, &c);
        tw[m] = make_double2(c, s);
    }
}

// ---------------------------------------------------------------------------
// Main kernel: per-PAIR-of-sequences. x columns read straight into registers
// (kept there for the tile phase — no seq LDS), fp64 radix-8 FFT (z = a+i*b),
// unpack mag^2, top-5 per series, periods/cycles, owner-writes tile rows.
// LDS = re/im only (~33 KB) -> 4 blocks/CU.
// ---------------------------------------------------------------------------
__global__ __launch_bounds__(256, 4) void pt_fft_tiles(const float* __restrict__ x,
                                                       float* __restrict__ out,
                                                       const double2* __restrict__ tw) {
    __shared__ double re[2048];
    __shared__ double im[2048];
    __shared__ double wredv[4];
    __shared__ int    wredi[4];
    __shared__ int sh_take[2][K_];

    // XCD-aware swizzle: blocks with equal (blockIdx & 7) (likely same XCD)
    // get consecutive q -> adjacent x columns -> L2 line reuse.
    const int i0  = blockIdx.x;
    const int q   = ((i0 & 7) << 8) | (i0 >> 3);
    const int bn0 = q * 2;
    const int b   = bn0 >> 7;          // / N_
    const int n   = bn0 & 127;         // even
    const int tid = threadIdx.x;

    // ---- Load x columns (n, n+1) into registers (8 float2, batched issue).
    const float* xp = x + (size_t)b * T_ * N_ + n;
    float2 v[8];
#pragma unroll
    for (int m = 0; m < 8; ++m)
        v[m] = *(const float2*)(xp + (size_t)(tid + 256 * m) * N_);

    // Bit-reversed complex pack into LDS.
#pragma unroll
    for (int m = 0; m < 8; ++m) {
        const int t = tid + 256 * m;
        const int p = sw((int)(__brev((unsigned)t) >> 21));   // pos = rev11(t)
        re[p] = (double)v[m].x;
        im[p] = (double)v[m].y;
    }
    __syncthreads();

    // ---- Round 1: radix-8 (stages 1-3), h=1, constant twiddles.
    {
        const int base = tid * 8;
        cd E[8];
#pragma unroll
        for (int j = 0; j < 8; ++j) { const int p = sw(base + j); E[j].r = re[p]; E[j].i = im[p]; }
        bf_1(E[0], E[1]); bf_1(E[2], E[3]); bf_1(E[4], E[5]); bf_1(E[6], E[7]);
        bf_1(E[0], E[2]); bf_mi(E[1], E[3]); bf_1(E[4], E[6]); bf_mi(E[5], E[7]);
        bf_1(E[0], E[4]); bf_w(E[1], E[5], S2_D, -S2_D);
        bf_mi(E[2], E[6]); bf_w(E[3], E[7], -S2_D, -S2_D);
#pragma unroll
        for (int j = 0; j < 8; ++j) { const int p = sw(base + j); re[p] = E[j].r; im[p] = E[j].i; }
    }
    __syncthreads();

    // ---- Rounds 2,3: radix-8 at stages s=4 (h=8) and s=7 (h=64).
#pragma unroll
    for (int r = 0; r < 2; ++r) {
        const int s    = 4 + 3 * r;
        const int h    = 1 << (s - 1);
        const int bq   = tid & (h - 1);
        const int g    = tid >> (s - 1);
        const int base = g * 8 * h + bq;
        const double2 w1  = tw[bq << (11 - s)];
        const double2 w2a = tw[bq << (10 - s)];
        const double2 w2b = tw[(bq + h) << (10 - s)];
        const double2 w30 = tw[bq << (9 - s)];
        const double2 w31 = tw[(bq + h) << (9 - s)];
        const double2 w32 = tw[(bq + 2 * h) << (9 - s)];
        const double2 w33 = tw[(bq + 3 * h) << (9 - s)];
        cd E[8];
#pragma unroll
        for (int j = 0; j < 8; ++j) { const int p = sw(base + j * h); E[j].r = re[p]; E[j].i = im[p]; }
        bf_w(E[0], E[1], w1.x, w1.y);   bf_w(E[2], E[3], w1.x, w1.y);
        bf_w(E[4], E[5], w1.x, w1.y);   bf_w(E[6], E[7], w1.x, w1.y);
        bf_w(E[0], E[2], w2a.x, w2a.y); bf_w(E[1], E[3], w2b.x, w2b.y);
        bf_w(E[4], E[6], w2a.x, w2a.y); bf_w(E[5], E[7], w2b.x, w2b.y);
        bf_w(E[0], E[4], w30.x, w30.y); bf_w(E[1], E[5], w31.x, w31.y);
        bf_w(E[2], E[6], w32.x, w32.y); bf_w(E[3], E[7], w33.x, w33.y);
#pragma unroll
        for (int j = 0; j < 8; ++j) { const int p = sw(base + j * h); re[p] = E[j].r; im[p] = E[j].i; }
        __syncthreads();
    }

    // ---- Round 4: radix-4 (stages 10-11), h=512, 2 butterflies/thread.
#pragma unroll
    for (int u = 0; u < 2; ++u) {
        const int bb = tid + 256 * u;
        const double2 wA = tw[bb << 1];
        const double2 wB = tw[bb];
        const double2 wC = tw[bb + 512];
        const int p0 = sw(bb), p1 = sw(bb + 512), p2 = sw(bb + 1024), p3 = sw(bb + 1536);
        cd E0 = {re[p0], im[p0]}, E1 = {re[p1], im[p1]};
        cd E2 = {re[p2], im[p2]}, E3 = {re[p3], im[p3]};
        bf_w(E0, E1, wA.x, wA.y); bf_w(E2, E3, wA.x, wA.y);
        bf_w(E0, E2, wB.x, wB.y); bf_w(E1, E3, wC.x, wC.y);
        re[p0] = E0.r; im[p0] = E0.i; re[p1] = E1.r; im[p1] = E1.i;
        re[p2] = E2.r; im[p2] = E2.i; re[p3] = E3.r; im[p3] = E3.i;
    }
    __syncthreads();

    // ---- Unpack both spectra; 4*mag^2 (uniform scale, rank-preserving).
    double magsA[4], magsB[4];
#pragma unroll
    for (int m = 0; m < 4; ++m) {
        const int k  = 1 + tid + 256 * m;          // 1..1024
        const int nk = 2048 - k;
        const int pk = sw(k), pn = sw(nk);
        const double zr = re[pk], zi = im[pk];
        const double yr = re[pn], yi = im[pn];
        const double ar = zr + yr, ai = zi - yi;
        const double br = zi + yi, bi = yr - zr;
        magsA[m] = ar * ar + ai * ai;
        magsB[m] = br * br + bi * bi;
    }
    __syncthreads();
#pragma unroll
    for (int m = 0; m < 4; ++m) {
        const int pk = sw(1 + tid + 256 * m);
        re[pk] = magsA[m];
        im[pk] = magsB[m];
    }
    __syncthreads();

    // ---- Top-5: threads 0..127 -> A (re), 128..255 -> B (im); shuffle reduce.
    const int half = tid >> 7;
    const int lt   = tid & 127;
    const int wid  = tid >> 6;
    double* marr = half ? im : re;
    for (int it = 0; it < K_; ++it) {
        double bestv = -2.0;
        int    besti = 1 << 30;
#pragma unroll
        for (int m = 0; m < 8; ++m) {
            const int k = 1 + lt + 128 * m;        // 1..1024
            const double vv = marr[sw(k)];
            if (vv > bestv || (vv == bestv && k < besti)) { bestv = vv; besti = k; }
        }
#pragma unroll
        for (int off = 32; off > 0; off >>= 1) {
            const double v2 = __shfl_down(bestv, off);
            const int    i2 = __shfl_down(besti, off);
            if (v2 > bestv || (v2 == bestv && i2 < besti)) { bestv = v2; besti = i2; }
        }
        if ((tid & 63) == 0) { wredv[wid] = bestv; wredi[wid] = besti; }
        __syncthreads();
        if (lt == 0) {
            double vb = wredv[2 * half]; int ib = wredi[2 * half];
            const double v1 = wredv[2 * half + 1]; const int i1 = wredi[2 * half + 1];
            if (v1 > vb || (v1 == vb && i1 < ib)) { vb = v1; ib = i1; }
            marr[sw(ib)] = -1.0;                   // exclude for next iter
            int period = T_ / ib;
            if (period > PMAX_) period = PMAX_;
            if (period < MINP_) period = MINP_;
            const int cyc = T_ / period;
            sh_take[half][it] = (period << 16) | (period * cyc); // pack period|take
        }
        __syncthreads();
    }

    // ---- periods / cycles (ints as float32).
    const size_t TILES = (size_t)BN_ * K_ * T_;
    if (tid < 2 * K_) {
        const int s2 = tid / K_, k2 = tid % K_;
        const int pk   = sh_take[s2][k2];
        const int per  = pk >> 16;
        const int take = pk & 0xFFFF;
        out[TILES + (size_t)(bn0 + s2) * K_ + k2]                      = (float)per;
        out[TILES + (size_t)BN_ * K_ + (size_t)(bn0 + s2) * K_ + k2]   = (float)(take / per);
    }

    // ---- Tile rows: owner-writes from registers. For output row (s2,k):
    //   p = (t >= start) ? t - start : t + take;  val = (t >= start) ? seq[t] : 0
    // Bijection onto [0,T); lane-consecutive t -> consecutive p (coalesced).
    float* rowA = out + (size_t)bn0 * (K_ * T_);
#pragma unroll
    for (int s2 = 0; s2 < 2; ++s2) {
#pragma unroll
        for (int k = 0; k < K_; ++k) {
            const int take  = sh_take[s2][k] & 0xFFFF;
            const int start = T_ - take;
            float* dst = rowA + (size_t)(s2 * K_ + k) * T_;
#pragma unroll
            for (int m = 0; m < 8; ++m) {
                const int t   = tid + 256 * m;
                const bool lo = (t < start);
                const int p   = lo ? (t + take) : (t - start);
                const float val = lo ? 0.0f : (s2 ? v[m].y : v[m].x);
                __builtin_nontemporal_store(val, dst + p);
            }
        }
    }
}

// ---------------------------------------------------------------------------
extern "C" void kernel_launch(void* const* d_in, const int* in_sizes, int n_in,
                              void* d_out, int out_size, void* d_ws, size_t ws_size,
                              hipStream_t stream) {
    const float* x = (const float*)d_in[0];
    float* out = (float*)d_out;
    double2* tw = (double2*)d_ws;   // 16 KB twiddle table

    pt_twiddle<<<dim3(4), dim3(256), 0, stream>>>(tw);
    pt_fft_tiles<<<dim3(BN_ / 2), dim3(256), 0, stream>>>(x, out, tw);
}